// Round 9
// baseline (1528.840 us; speedup 1.0000x reference)
//
#include <hip/hip_runtime.h>
#include <math.h>

#define C_CH 54
#define CP   64      // row stride: [0..53]=-2*cand, 54=candsq, 55=0, 56=tcand, 57=libmean, 58..63=0
#define NT   20
#define NM   6
#define NK   120
#define BLK  256
#define PIXW 32            // pixels per wave (16 quads x 2)
#define PPB  128           // pixels per block (4 waves)

// quad_perm DPP helpers (VALU pipe, no LDS): butterfly over the 4 lanes of a quad
__device__ __forceinline__ float qxor1(float v) {
    return __int_as_float(__builtin_amdgcn_update_dpp(
        __float_as_int(v), __float_as_int(v), 0xB1, 0xF, 0xF, true)); // [1,0,3,2]
}
__device__ __forceinline__ float qxor2(float v) {
    return __int_as_float(__builtin_amdgcn_update_dpp(
        __float_as_int(v), __float_as_int(v), 0x4E, 0xF, 0xF, true)); // [2,3,0,1]
}

// ---------------- prep: scaled candidate table into workspace ----------------
__global__ __launch_bounds__(256) void hadar_prep(
    const float* __restrict__ s_sky, const float* __restrict__ s_ground,
    const float* __restrict__ library, const float* __restrict__ wg,
    float* __restrict__ cand)
{
    __shared__ float xamb[C_CH];
    __shared__ float tc[NT];
    __shared__ float lm[NM];
    const int tid = threadIdx.x;
    if (tid < NT) tc[tid] = 250.0f + (float)tid * (100.0f / 19.0f);
    if (tid < C_CH) xamb[tid] = 0.5f * s_sky[tid] + 0.5f * s_ground[tid];
    if (tid < NM) {
        float s = 0.0f;
        for (int c = 0; c < C_CH; ++c) s += library[tid * C_CH + c];
        lm[tid] = s / (float)C_CH;
    }
    __syncthreads();

    const float c1 = 1.191042e-8f, c2 = 1.4387752f;
    for (int idx = tid; idx < NK * CP; idx += 256) {
        const int k = idx >> 6, c = idx & 63;
        const int m = k / NT, t = k - m * NT;
        float v = 0.0f;
        if (c < C_CH) {
            const float nu = wg[c];
            const float B = c1 * nu * nu * nu / expm1f(c2 * nu / tc[t]);
            const float e = library[m * C_CH + c];
            v = -2.0f * (e * B + (1.0f - e) * xamb[c]);   // store -2*cand
        } else if (c == 56) v = tc[t];
        else if (c == 57) v = lm[m];
        cand[idx] = v;
    }
    __syncthreads();

    if (tid < NK) {
        // candsq from the scaled values: (-2v)^2 = 4v^2; x0.25 at the end is an
        // exact power-of-2 scaling, so this equals sum(v^2) bit-exactly in the
        // same sequential order as the reference.
        float s = 0.0f;
        for (int c = 0; c < C_CH; ++c) { float w = cand[tid * CP + c]; s += w * w; }
        cand[tid * CP + 54] = 0.25f * s;
    }
}

// ---------------- main: quad-per-pixel, per-lane channel chunks -----------------
// lane layout: px = lane>>2 (16 pixels/wave/p), g = lane&3 (16-channel chunk).
// Each k-iter loads the candidate row as 4 per-lane dwordx4 (L1-resident 30KB
// table, per-lane-parallel delivery), FMA-accumulates 16 channels per lane for
// 2 pixels, quad-butterfly (DPP, VALU pipe) gives key = candsq - 2*dot on all
// 4 lanes. argmin over key == argmin over loss (ssq is a per-pixel constant).
__global__ __launch_bounds__(BLK) void hadar_main(
    const float* __restrict__ s_obs,
    const float* __restrict__ library,
    const float* __restrict__ cand,
    float* __restrict__ out, float* __restrict__ partials, int N)
{
    const int tid  = threadIdx.x;
    const int wave = tid >> 6;
    const int lane = tid & 63;
    const int px   = lane >> 2;
    const int g    = lane & 3;
    const long long nb = (long long)blockIdx.x * PPB + wave * PIXW + px;

    float r[2][16];
    float ssq[2];
    #pragma unroll
    for (int p = 0; p < 2; ++p) {
        const long long n = nb + p * 16;
        #pragma unroll
        for (int j = 0; j < 16; ++j) r[p][j] = 0.0f;
        if (n < N) {
            const float* src = s_obs + n * C_CH + g * 16;
            if (g < 3) {
                #pragma unroll
                for (int j = 0; j < 8; ++j) {
                    float2 w = *(const float2*)(src + 2 * j);
                    r[p][2 * j] = w.x; r[p][2 * j + 1] = w.y;
                }
            } else {
                #pragma unroll
                for (int j = 0; j < 3; ++j) {
                    float2 w = *(const float2*)(src + 2 * j);
                    r[p][2 * j] = w.x; r[p][2 * j + 1] = w.y;
                }
            }
        }
        // per-pixel ssq via quad butterfly (before planting the 1.0)
        float s = 0.0f;
        #pragma unroll
        for (int j = 0; j < 16; ++j) s = fmaf(r[p][j], r[p][j], s);
        s += qxor1(s);
        s += qxor2(s);
        ssq[p] = s;
        // plant 1.0 against slot 54 (candsq) so the FMA chain adds +candsq
        if (g == 3) r[p][6] = 1.0f;
    }

    float bl[2] = { 3.4e38f, 3.4e38f };
    int   bk[2] = { 0, 0 };

    const float* cbase = cand + g * 16;
    #pragma unroll 2
    for (int k = 0; k < NK; ++k) {
        const float* cp = cbase + (size_t)k * CP;
        float cc[16];
        #pragma unroll
        for (int j = 0; j < 4; ++j) {
            float4 w = *(const float4*)(cp + 4 * j);
            cc[4 * j] = w.x; cc[4 * j + 1] = w.y; cc[4 * j + 2] = w.z; cc[4 * j + 3] = w.w;
        }
        float a0[4] = {0.f, 0.f, 0.f, 0.f};
        float a1[4] = {0.f, 0.f, 0.f, 0.f};
        #pragma unroll
        for (int j = 0; j < 16; ++j) {
            a0[j & 3] = fmaf(r[0][j], cc[j], a0[j & 3]);
            a1[j & 3] = fmaf(r[1][j], cc[j], a1[j & 3]);
        }
        float d0 = (a0[0] + a0[1]) + (a0[2] + a0[3]);
        float d1 = (a1[0] + a1[1]) + (a1[2] + a1[3]);
        d0 += qxor1(d0); d0 += qxor2(d0);   // all 4 lanes now hold identical key
        d1 += qxor1(d1); d1 += qxor2(d1);
        if (d0 < bl[0]) { bl[0] = d0; bk[0] = k; }
        if (d1 < bl[1]) { bl[1] = d1; bk[1] = k; }
    }

    // ---- outputs ----
    const size_t NN = (size_t)N;
    const size_t NC = (size_t)C_CH * NN;
    float lsum = 0.0f;
    #pragma unroll
    for (int p = 0; p < 2; ++p) {
        const long long n = nb + p * 16;
        if (n >= N) continue;
        const int k = bk[p];
        const int m = k / NT;
        const float* crow = cand + (size_t)k * CP;

        if (g == 0) {
            out[n]                 = crow[56];        // best_t
            out[NN + NC + n]       = 0.5f;            // best_v
            out[2 * NN + NC + n]   = 0.0f;            // beta
            out[3 * NN + NC + n]   = crow[57];        // texture
            lsum += ssq[p] + bl[p];                   // best_loss
        }

        const float* lrow = library + m * C_CH;
        float* eout = out + NN + (size_t)n * C_CH;
        float* rout = out + 4 * NN + NC + (size_t)n * C_CH;
        if (g < 3) {
            #pragma unroll
            for (int j = 0; j < 8; ++j) {
                const int c = g * 16 + 2 * j;
                *(float2*)(eout + c) = *(const float2*)(lrow + c);
                float2 w = *(const float2*)(crow + c);
                *(float2*)(rout + c) = make_float2(-0.5f * w.x, -0.5f * w.y);  // exact un-scale
            }
        } else {
            #pragma unroll
            for (int j = 0; j < 3; ++j) {
                const int c = 48 + 2 * j;
                *(float2*)(eout + c) = *(const float2*)(lrow + c);
                float2 w = *(const float2*)(crow + c);
                *(float2*)(rout + c) = make_float2(-0.5f * w.x, -0.5f * w.y);
            }
        }
    }

    // ---- deterministic block reduction of best_loss sum ----
    __shared__ float red[BLK];
    red[tid] = lsum;
    __syncthreads();
    #pragma unroll
    for (int s = BLK / 2; s > 0; s >>= 1) {
        if (tid < s) red[tid] += red[tid + s];
        __syncthreads();
    }
    if (tid == 0) partials[blockIdx.x] = red[0];
}

// ---------------- final reduce: objective = mean(best_loss) ----------------
__global__ __launch_bounds__(256) void hadar_reduce(
    const float* __restrict__ partials, int nb, float* __restrict__ obj_out, float invN)
{
    __shared__ float red[256];
    float s = 0.0f;
    for (int i = threadIdx.x; i < nb; i += 256) s += partials[i];
    red[threadIdx.x] = s;
    __syncthreads();
    #pragma unroll
    for (int st = 128; st > 0; st >>= 1) {
        if (threadIdx.x < st) red[threadIdx.x] += red[threadIdx.x + st];
        __syncthreads();
    }
    if (threadIdx.x == 0) *obj_out = red[0] * invN;
}

extern "C" void kernel_launch(void* const* d_in, const int* in_sizes, int n_in,
                              void* d_out, int out_size, void* d_ws, size_t ws_size,
                              hipStream_t stream)
{
    const float* s_obs    = (const float*)d_in[0];
    const float* s_sky    = (const float*)d_in[1];
    const float* s_ground = (const float*)d_in[2];
    const float* library  = (const float*)d_in[3];
    const float* wg       = (const float*)d_in[4];
    float* out = (float*)d_out;

    const int N  = in_sizes[0] / C_CH;
    const int nb = (N + PPB - 1) / PPB;

    float* ws       = (float*)d_ws;
    float* cand     = ws;              // NK*CP = 7680 floats
    float* partials = ws + 8192;       // nb floats

    hadar_prep<<<1, 256, 0, stream>>>(s_sky, s_ground, library, wg, cand);
    hadar_main<<<nb, BLK, 0, stream>>>(s_obs, library, cand, out, partials, N);

    const size_t NN = (size_t)N;
    float* obj_out = out + 4 * NN + 2 * (size_t)C_CH * NN;
    hadar_reduce<<<1, 256, 0, stream>>>(partials, nb, obj_out, 1.0f / (float)N);
}